// Round 2
// baseline (3653.794 us; speedup 1.0000x reference)
//
#include <hip/hip_runtime.h>

#define BB 65536
#define LL 128
#define HH 20
#define HH2 2

__device__ __forceinline__ float fexp(float x) {
    return __builtin_amdgcn_exp2f(x * 1.4426950408889634f);   // e^x via 2^(x*log2e)
}
__device__ __forceinline__ float frcp(float x) { return __builtin_amdgcn_rcpf(x); }
__device__ __forceinline__ float sigf(float x) { return frcp(1.0f + fexp(-x)); }
__device__ __forceinline__ float tanh_(float x) { return 1.0f - 2.0f * frcp(fexp(2.0f * x) + 1.0f); }
__device__ __forceinline__ float lrelu(float x) { return fmaxf(x, 0.01f * x); }
__device__ __forceinline__ void fma4(float4& a, float s, const float4 w) {
    a.x = fmaf(s, w.x, a.x);
    a.y = fmaf(s, w.y, a.y);
    a.z = fmaf(s, w.z, a.z);
    a.w = fmaf(s, w.w, a.w);
}
// swap adjacent lanes (0<->1, 2<->3, ...) via DPP quad_perm [1,0,3,2] — pure VALU, no LDS pipe
__device__ __forceinline__ float dpp_swap(float x) {
    int i = __builtin_bit_cast(int, x);
    int r = __builtin_amdgcn_update_dpp(0, i, 0xB1, 0xF, 0xF, true);
    return __builtin_bit_cast(float, r);
}

// Two threads per batch element (adjacent lanes). half = lane&1.
//   layer 1: thread computes j = half*10 .. half*10+9  (10 of 20 gate-groups)
//   layer 2: thread computes gate row j2 = half        (1 of 2)
// Per-step exchange of h1n/c1n (10+10) + h2 (1) via DPP pair swap.
//
// Weights packed gate-major into LDS float4s:
// sW1[j][k].{x,y,z,w} = W[gate*20+j][k'] for gate = i,f,g,o
//   k = 0,1 : Wih1 cols; k = 2..21 : Whh1 cols; k = 22 : bih1+bhh1
// sW2[j][k]: k=0..39 out1 cols, k=40,41 h2 cols, k=42 bias.
__global__ __launch_bounds__(256, 2) void sampler_lstm(
    const float* __restrict__ mu, const float* __restrict__ log_var,
    const float* __restrict__ eps0, const float* __restrict__ eps,
    const float* __restrict__ Wih1, const float* __restrict__ Whh1,
    const float* __restrict__ bih1, const float* __restrict__ bhh1,
    const float* __restrict__ Wih2, const float* __restrict__ Whh2,
    const float* __restrict__ bih2, const float* __restrict__ bhh2,
    float* __restrict__ out)
{
    __shared__ float4 sW1[HH][23];
    __shared__ float4 sW2[HH2][43];

    const int tid = threadIdx.x;
    for (int idx = tid; idx < HH * 23; idx += 256) {
        int j = idx / 23, k = idx % 23;
        float4 v;
        float* vp = (float*)&v;
        #pragma unroll
        for (int g = 0; g < 4; ++g) {
            int row = g * HH + j;
            float val;
            if (k < 2)       val = Wih1[row * 2 + k];
            else if (k < 22) val = Whh1[row * HH + (k - 2)];
            else             val = bih1[row] + bhh1[row];
            vp[g] = val;
        }
        sW1[j][k] = v;
    }
    for (int idx = tid; idx < HH2 * 43; idx += 256) {
        int j = idx / 43, k = idx % 43;
        float4 v;
        float* vp = (float*)&v;
        #pragma unroll
        for (int g = 0; g < 4; ++g) {
            int row = g * HH2 + j;
            float val;
            if (k < 40)      val = Wih2[row * 40 + k];
            else if (k < 42) val = Whh2[row * 2 + (k - 40)];
            else             val = bih2[row] + bhh2[row];
            vp[g] = val;
        }
        sW2[j][k] = v;
    }
    __syncthreads();

    const int gtid = blockIdx.x * 256 + tid;
    const int b    = gtid >> 1;
    const int half = gtid & 1;

    const float* murow = mu + (size_t)b * LL;
    float* out_mu = out + (size_t)b * LL;
    float* out_lv = out_mu + (size_t)BB * LL;
    float* out_sp = out_mu + 2ul * (size_t)BB * LL;

    const float4* __restrict__ w1base = &sW1[half * 10][0];   // own 10 rows
    const float4* __restrict__ w2row  = &sW2[half][0];        // own layer-2 gate row

    float h1[HH];                 // full h1 state (post-exchange)
    float c1own[10];              // own-half c1 state
    #pragma unroll
    for (int j = 0; j < HH; ++j) h1[j] = 0.f;
    #pragma unroll
    for (int j = 0; j < 10; ++j) c1own[j] = 0.f;
    float h2a = 0.f, h2b = 0.f, c2own = 0.f;

    float x0 = eps0[b] * fexp(0.5f * log_var[(size_t)b * LL]) + murow[0];
    float x1 = 0.f;

    #pragma unroll 1
    for (int t = 0; t < LL; ++t) {
        float mu_t  = murow[t];
        float eps_t = eps[(size_t)t * BB + b];

        // ---- layer 1 (own 10 gate-groups) ----
        float h1n[10];
        #pragma unroll
        for (int jj = 0; jj < 10; ++jj) {
            const float4* wrow = w1base + (size_t)jj * 23;
            float4 a = wrow[22];
            fma4(a, x0, wrow[0]);
            fma4(a, x1, wrow[1]);
            #pragma unroll
            for (int k = 0; k < HH; ++k) fma4(a, h1[k], wrow[2 + k]);
            float cn = sigf(a.y) * c1own[jj] + sigf(a.x) * tanh_(a.z);
            c1own[jj] = cn;
            h1n[jj] = sigf(a.w) * tanh_(cn);
        }

        // ---- exchange with partner lane, rebuild full arrays ----
        float o1h[HH], o1c[HH];
        #pragma unroll
        for (int jj = 0; jj < 10; ++jj) {
            float ho = dpp_swap(h1n[jj]);
            float co = dpp_swap(c1own[jj]);
            float h_lo = half ? ho        : h1n[jj];   // j = jj
            float h_hi = half ? h1n[jj]   : ho;        // j = 10+jj
            float c_lo = half ? co        : c1own[jj];
            float c_hi = half ? c1own[jj] : co;
            h1[jj]      = h_lo;
            h1[10 + jj] = h_hi;
            o1h[jj]      = lrelu(h_lo);
            o1h[10 + jj] = lrelu(h_hi);
            o1c[jj]      = lrelu(c_lo);
            o1c[10 + jj] = lrelu(c_hi);
        }

        // ---- layer 2 (own gate row) ----
        float4 a = w2row[42];
        #pragma unroll
        for (int k = 0; k < HH; ++k) fma4(a, o1h[k], w2row[k]);
        #pragma unroll
        for (int k = 0; k < HH; ++k) fma4(a, o1c[k], w2row[20 + k]);
        fma4(a, h2a, w2row[40]);
        fma4(a, h2b, w2row[41]);
        float cn = sigf(a.y) * c2own + sigf(a.x) * tanh_(a.z);
        c2own = cn;
        float h2own = sigf(a.w) * tanh_(cn);
        float h2oth = dpp_swap(h2own);
        h2a = half ? h2oth : h2own;
        h2b = half ? h2own : h2oth;

        if (!half) {
            out_mu[t] = h2a;
            out_sp[t] = eps_t * fexp(0.5f * h2b) + h2a;
        } else {
            out_lv[t] = h2b;
        }

        x0 = mu_t;
        x1 = (float)t;
    }
}

extern "C" void kernel_launch(void* const* d_in, const int* in_sizes, int n_in,
                              void* d_out, int out_size, void* d_ws, size_t ws_size,
                              hipStream_t stream) {
    sampler_lstm<<<dim3(BB * 2 / 256), dim3(256), 0, stream>>>(
        (const float*)d_in[0],  (const float*)d_in[1],  (const float*)d_in[2],
        (const float*)d_in[3],  (const float*)d_in[4],  (const float*)d_in[5],
        (const float*)d_in[6],  (const float*)d_in[7],  (const float*)d_in[8],
        (const float*)d_in[9],  (const float*)d_in[10], (const float*)d_in[11],
        (float*)d_out);
}

// Round 3
// 2033.455 us; speedup vs baseline: 1.7968x; 1.7968x over previous
//
#include <hip/hip_runtime.h>

#define BB 65536
#define LL 128
#define HH 20
#define HH2 2

__device__ __forceinline__ float fexp(float x) {
    return __builtin_amdgcn_exp2f(x * 1.4426950408889634f);   // e^x via 2^(x*log2e)
}
__device__ __forceinline__ float frcp(float x) { return __builtin_amdgcn_rcpf(x); }
__device__ __forceinline__ float sigf(float x) { return frcp(1.0f + fexp(-x)); }
__device__ __forceinline__ float tanh_(float x) { return 1.0f - 2.0f * frcp(fexp(2.0f * x) + 1.0f); }
__device__ __forceinline__ float lrelu(float x) { return fmaxf(x, 0.01f * x); }
__device__ __forceinline__ void fma4(float4& a, float s, const float4 w) {
    a.x = fmaf(s, w.x, a.x);
    a.y = fmaf(s, w.y, a.y);
    a.z = fmaf(s, w.z, a.z);
    a.w = fmaf(s, w.w, a.w);
}
// swap adjacent lanes (0<->1, 2<->3, ...) via DPP quad_perm [1,0,3,2] — pure VALU
__device__ __forceinline__ float dpp_swap(float x) {
    int i = __builtin_bit_cast(int, x);
    int r = __builtin_amdgcn_update_dpp(0, i, 0xB1, 0xF, 0xF, true);
    return __builtin_bit_cast(float, r);
}

// Two threads per batch element (adjacent lanes), half = lane&1.
//   layer 1: thread computes global gate-groups j = half*10 .. half*10+9
//   layer 2: thread computes gate row j2 = half
// Layer-2 accumulation is FUSED into the exchange loop so no o1h/o1c arrays
// exist — live state is h1lo[10]+h1hi[10]+c1own[10]+scalars (~45 regs).
//
// LDS weight packing (gate-major float4):
// sW1[j][k].{x,y,z,w} = W[gate*20+j][col] for gate = i,f,g,o
//   k = 0,1 : Wih1 cols; k = 2..21 : Whh1 cols; k = 22 : bih1+bhh1
// sW2[j][k]: k=0..19 out1-h cols, 20..39 out1-c cols, 40,41 h2 cols, 42 bias.
__global__ __launch_bounds__(256) void sampler_lstm(
    const float* __restrict__ mu, const float* __restrict__ log_var,
    const float* __restrict__ eps0, const float* __restrict__ eps,
    const float* __restrict__ Wih1, const float* __restrict__ Whh1,
    const float* __restrict__ bih1, const float* __restrict__ bhh1,
    const float* __restrict__ Wih2, const float* __restrict__ Whh2,
    const float* __restrict__ bih2, const float* __restrict__ bhh2,
    float* __restrict__ out)
{
    __shared__ float4 sW1[HH][23];
    __shared__ float4 sW2[HH2][43];

    const int tid = threadIdx.x;
    for (int idx = tid; idx < HH * 23; idx += 256) {
        int j = idx / 23, k = idx % 23;
        float4 v;
        float* vp = (float*)&v;
        #pragma unroll
        for (int g = 0; g < 4; ++g) {
            int row = g * HH + j;
            float val;
            if (k < 2)       val = Wih1[row * 2 + k];
            else if (k < 22) val = Whh1[row * HH + (k - 2)];
            else             val = bih1[row] + bhh1[row];
            vp[g] = val;
        }
        sW1[j][k] = v;
    }
    for (int idx = tid; idx < HH2 * 43; idx += 256) {
        int j = idx / 43, k = idx % 43;
        float4 v;
        float* vp = (float*)&v;
        #pragma unroll
        for (int g = 0; g < 4; ++g) {
            int row = g * HH2 + j;
            float val;
            if (k < 40)      val = Wih2[row * 40 + k];
            else if (k < 42) val = Whh2[row * 2 + (k - 40)];
            else             val = bih2[row] + bhh2[row];
            vp[g] = val;
        }
        sW2[j][k] = v;
    }
    __syncthreads();

    const int gtid = blockIdx.x * 256 + tid;
    const int b    = gtid >> 1;
    const int half = gtid & 1;
    const bool hi  = (half != 0);

    const float* murow = mu + (size_t)b * LL;
    float* out_mu = out + (size_t)b * LL;
    float* out_lv = out_mu + (size_t)BB * LL;
    float* out_sp = out_mu + 2ul * (size_t)BB * LL;

    const float4* __restrict__ w1base = &sW1[half * 10][0];   // own 10 gate-group rows
    const float4* __restrict__ w2row  = &sW2[half][0];        // own layer-2 gate row

    float h1lo[10], h1hi[10], c1own[10];
    #pragma unroll
    for (int j = 0; j < 10; ++j) { h1lo[j] = 0.f; h1hi[j] = 0.f; c1own[j] = 0.f; }
    float h2a = 0.f, h2b = 0.f, c2own = 0.f;

    float x0 = eps0[b] * fexp(0.5f * log_var[(size_t)b * LL]) + murow[0];
    float x1 = 0.f;

    #pragma unroll 1
    for (int t = 0; t < LL; ++t) {
        float mu_t  = murow[t];
        float eps_t = eps[(size_t)t * BB + b];

        // ---- layer 1: own 10 gate-groups ----
        float h1n[10];
        #pragma unroll
        for (int jj = 0; jj < 10; ++jj) {
            const float4* wrow = w1base + (size_t)jj * 23;
            float4 a = wrow[22];
            fma4(a, x0, wrow[0]);
            fma4(a, x1, wrow[1]);
            #pragma unroll
            for (int k = 0; k < 10; ++k) fma4(a, h1lo[k], wrow[2 + k]);
            #pragma unroll
            for (int k = 0; k < 10; ++k) fma4(a, h1hi[k], wrow[12 + k]);
            float cn = sigf(a.y) * c1own[jj] + sigf(a.x) * tanh_(a.z);
            c1own[jj] = cn;
            h1n[jj] = sigf(a.w) * tanh_(cn);
        }

        // ---- exchange + fused layer-2 accumulation ----
        float4 a2 = w2row[42];                         // layer-2 bias (i,f,g,o)
        #pragma unroll
        for (int jj = 0; jj < 10; ++jj) {
            float ho = dpp_swap(h1n[jj]);
            float co = dpp_swap(c1own[jj]);
            float h_lo = hi ? ho        : h1n[jj];     // global j = jj
            float h_hi = hi ? h1n[jj]   : ho;          // global j = 10+jj
            float c_lo = hi ? co        : c1own[jj];
            float c_hi = hi ? c1own[jj] : co;
            h1lo[jj] = h_lo;
            h1hi[jj] = h_hi;
            fma4(a2, lrelu(h_lo), w2row[jj]);
            fma4(a2, lrelu(h_hi), w2row[10 + jj]);
            fma4(a2, lrelu(c_lo), w2row[20 + jj]);
            fma4(a2, lrelu(c_hi), w2row[30 + jj]);
        }
        fma4(a2, h2a, w2row[40]);
        fma4(a2, h2b, w2row[41]);

        // ---- layer 2 gates (own row) ----
        float cn = sigf(a2.y) * c2own + sigf(a2.x) * tanh_(a2.z);
        c2own = cn;
        float h2own = sigf(a2.w) * tanh_(cn);
        float h2oth = dpp_swap(h2own);
        h2a = hi ? h2oth : h2own;
        h2b = hi ? h2own : h2oth;

        if (!hi) {
            out_mu[t] = h2a;
            out_sp[t] = eps_t * fexp(0.5f * h2b) + h2a;
        } else {
            out_lv[t] = h2b;
        }

        x0 = mu_t;
        x1 = (float)t;
    }
}

extern "C" void kernel_launch(void* const* d_in, const int* in_sizes, int n_in,
                              void* d_out, int out_size, void* d_ws, size_t ws_size,
                              hipStream_t stream) {
    sampler_lstm<<<dim3(BB * 2 / 256), dim3(256), 0, stream>>>(
        (const float*)d_in[0],  (const float*)d_in[1],  (const float*)d_in[2],
        (const float*)d_in[3],  (const float*)d_in[4],  (const float*)d_in[5],
        (const float*)d_in[6],  (const float*)d_in[7],  (const float*)d_in[8],
        (const float*)d_in[9],  (const float*)d_in[10], (const float*)d_in[11],
        (float*)d_out);
}

// Round 4
// 848.290 us; speedup vs baseline: 4.3072x; 2.3971x over previous
//
#include <hip/hip_runtime.h>

#define BB 65536
#define LL 128
#define HH 20
#define HH2 2

__device__ __forceinline__ float fexp(float x) {
    return __builtin_amdgcn_exp2f(x * 1.4426950408889634f);   // e^x via 2^(x*log2e)
}
__device__ __forceinline__ float frcp(float x) { return __builtin_amdgcn_rcpf(x); }
__device__ __forceinline__ float sigf(float x) { return frcp(1.0f + fexp(-x)); }
__device__ __forceinline__ float tanh_(float x) { return 1.0f - 2.0f * frcp(fexp(2.0f * x) + 1.0f); }
__device__ __forceinline__ float lrelu(float x) { return fmaxf(x, 0.01f * x); }
__device__ __forceinline__ void fma4(float4& a, float s, const float4 w) {
    a.x = fmaf(s, w.x, a.x);
    a.y = fmaf(s, w.y, a.y);
    a.z = fmaf(s, w.z, a.z);
    a.w = fmaf(s, w.w, a.w);
}
// swap adjacent lanes (0<->1, 2<->3, ...) via DPP quad_perm [1,0,3,2] — pure VALU
__device__ __forceinline__ float dpp_swap(float x) {
    int i = __builtin_bit_cast(int, x);
    int r = __builtin_amdgcn_update_dpp(0, i, 0xB1, 0xF, 0xF, true);
    return __builtin_bit_cast(float, r);
}

// Two threads per batch element (adjacent lanes), half = lane&1.
//   layer 1: thread computes global gate-groups j = half*10 .. half*10+9
//   layer 2: thread computes gate row j2 = half
// Layer-2 accumulation fused into the exchange loop (no o1 arrays).
//
// VGPR budget: __launch_bounds__(256,2) caps at 128 (the HW occupancy cliff:
// 196 VGPRs ran at 1 wave/SIMD in R2; need <=128 for 2 waves/SIMD).
// #pragma unroll 2 on the gate-group loop keeps only 2 live float4 accs.
//
// LDS weight packing (gate-major float4):
// sW1[j][k].{x,y,z,w} = W[gate*20+j][col] for gate = i,f,g,o
//   k = 0,1 : Wih1 cols; k = 2..21 : Whh1 cols; k = 22 : bih1+bhh1
// sW2[j][k]: k=0..19 out1-h cols, 20..39 out1-c cols, 40,41 h2 cols, 42 bias.
__global__ __launch_bounds__(256, 2) void sampler_lstm(
    const float* __restrict__ mu, const float* __restrict__ log_var,
    const float* __restrict__ eps0, const float* __restrict__ eps,
    const float* __restrict__ Wih1, const float* __restrict__ Whh1,
    const float* __restrict__ bih1, const float* __restrict__ bhh1,
    const float* __restrict__ Wih2, const float* __restrict__ Whh2,
    const float* __restrict__ bih2, const float* __restrict__ bhh2,
    float* __restrict__ out)
{
    __shared__ float4 sW1[HH][23];
    __shared__ float4 sW2[HH2][43];

    const int tid = threadIdx.x;
    for (int idx = tid; idx < HH * 23; idx += 256) {
        int j = idx / 23, k = idx % 23;
        float4 v;
        float* vp = (float*)&v;
        #pragma unroll
        for (int g = 0; g < 4; ++g) {
            int row = g * HH + j;
            float val;
            if (k < 2)       val = Wih1[row * 2 + k];
            else if (k < 22) val = Whh1[row * HH + (k - 2)];
            else             val = bih1[row] + bhh1[row];
            vp[g] = val;
        }
        sW1[j][k] = v;
    }
    for (int idx = tid; idx < HH2 * 43; idx += 256) {
        int j = idx / 43, k = idx % 43;
        float4 v;
        float* vp = (float*)&v;
        #pragma unroll
        for (int g = 0; g < 4; ++g) {
            int row = g * HH2 + j;
            float val;
            if (k < 40)      val = Wih2[row * 40 + k];
            else if (k < 42) val = Whh2[row * 2 + (k - 40)];
            else             val = bih2[row] + bhh2[row];
            vp[g] = val;
        }
        sW2[j][k] = v;
    }
    __syncthreads();

    const int gtid = blockIdx.x * 256 + tid;
    const int b    = gtid >> 1;
    const int half = gtid & 1;
    const bool hi  = (half != 0);

    const float* murow = mu + (size_t)b * LL;
    float* out_mu = out + (size_t)b * LL;
    float* out_lv = out_mu + (size_t)BB * LL;
    float* out_sp = out_mu + 2ul * (size_t)BB * LL;

    const float4* __restrict__ w1base = &sW1[half * 10][0];   // own 10 gate-group rows
    const float4* __restrict__ w2row  = &sW2[half][0];        // own layer-2 gate row

    float h1lo[10], h1hi[10], c1own[10];
    #pragma unroll
    for (int j = 0; j < 10; ++j) { h1lo[j] = 0.f; h1hi[j] = 0.f; c1own[j] = 0.f; }
    float h2a = 0.f, h2b = 0.f, c2own = 0.f;

    float x0 = eps0[b] * fexp(0.5f * log_var[(size_t)b * LL]) + murow[0];
    float x1 = 0.f;

    #pragma unroll 1
    for (int t = 0; t < LL; ++t) {
        float mu_t  = murow[t];
        float eps_t = eps[(size_t)t * BB + b];

        // ---- layer 1: own 10 gate-groups (unroll 2 -> low VGPR pressure) ----
        float h1n[10];
        #pragma unroll 2
        for (int jj = 0; jj < 10; ++jj) {
            const float4* wrow = w1base + (size_t)jj * 23;
            float4 a = wrow[22];
            fma4(a, x0, wrow[0]);
            fma4(a, x1, wrow[1]);
            #pragma unroll
            for (int k = 0; k < 10; ++k) fma4(a, h1lo[k], wrow[2 + k]);
            #pragma unroll
            for (int k = 0; k < 10; ++k) fma4(a, h1hi[k], wrow[12 + k]);
            float cn = sigf(a.y) * c1own[jj] + sigf(a.x) * tanh_(a.z);
            c1own[jj] = cn;
            h1n[jj] = sigf(a.w) * tanh_(cn);
        }

        // ---- exchange + fused layer-2 accumulation ----
        float4 a2 = w2row[42];                         // layer-2 bias (i,f,g,o)
        #pragma unroll 2
        for (int jj = 0; jj < 10; ++jj) {
            float ho = dpp_swap(h1n[jj]);
            float co = dpp_swap(c1own[jj]);
            float h_lo = hi ? ho        : h1n[jj];     // global j = jj
            float h_hi = hi ? h1n[jj]   : ho;          // global j = 10+jj
            float c_lo = hi ? co        : c1own[jj];
            float c_hi = hi ? c1own[jj] : co;
            h1lo[jj] = h_lo;
            h1hi[jj] = h_hi;
            fma4(a2, lrelu(h_lo), w2row[jj]);
            fma4(a2, lrelu(h_hi), w2row[10 + jj]);
            fma4(a2, lrelu(c_lo), w2row[20 + jj]);
            fma4(a2, lrelu(c_hi), w2row[30 + jj]);
        }
        fma4(a2, h2a, w2row[40]);
        fma4(a2, h2b, w2row[41]);

        // ---- layer 2 gates (own row) ----
        float cn = sigf(a2.y) * c2own + sigf(a2.x) * tanh_(a2.z);
        c2own = cn;
        float h2own = sigf(a2.w) * tanh_(cn);
        float h2oth = dpp_swap(h2own);
        h2a = hi ? h2oth : h2own;
        h2b = hi ? h2own : h2oth;

        if (!hi) {
            out_mu[t] = h2a;
            out_sp[t] = eps_t * fexp(0.5f * h2b) + h2a;
        } else {
            out_lv[t] = h2b;
        }

        x0 = mu_t;
        x1 = (float)t;
    }
}

extern "C" void kernel_launch(void* const* d_in, const int* in_sizes, int n_in,
                              void* d_out, int out_size, void* d_ws, size_t ws_size,
                              hipStream_t stream) {
    sampler_lstm<<<dim3(BB * 2 / 256), dim3(256), 0, stream>>>(
        (const float*)d_in[0],  (const float*)d_in[1],  (const float*)d_in[2],
        (const float*)d_in[3],  (const float*)d_in[4],  (const float*)d_in[5],
        (const float*)d_in[6],  (const float*)d_in[7],  (const float*)d_in[8],
        (const float*)d_in[9],  (const float*)d_in[10], (const float*)d_in[11],
        (float*)d_out);
}